// Round 14
// baseline (445.409 us; speedup 1.0000x reference)
//
#include <hip/hip_runtime.h>
#include <hip/hip_bf16.h>
#include <hip/hip_cooperative_groups.h>

namespace cg = cooperative_groups;

#define N_NODES   20000
#define N_EDGES   320000
#define DIM       256
#define N_GRAPHS  64
#define N_CLASSES 10
#define N_CH      32                   // feature chunks of 8
#define NP8       (N_NODES * 8)        // bytes per fp8 plane (160000) = LDS stage size
#define NP16      (N_NODES * 8)        // ushorts per bf16 plane (320000 B)
#define SLOT      64                   // fixed CSR slots per node (max deg+1 = 41 << 64)
#define DUMMY     N_NODES              // pad index -> zeroed row in LDS
#define CONV_THR  512                  // 8 waves/block in the cooperative conv kernel
#define NTILE     (N_NODES / 16)       // 1250 gemm tiles of 16 rows

typedef short  bf16x8 __attribute__((ext_vector_type(8)));
typedef float  f32x4  __attribute__((ext_vector_type(4)));
typedef float  f32x2  __attribute__((ext_vector_type(2)));

__device__ __forceinline__ float b2f(ushort u) {
    return __uint_as_float(((unsigned)u) << 16);
}
__device__ __forceinline__ ushort f2b(float f) {
    unsigned u = __float_as_uint(f);
    u += 0x7FFF + ((u >> 16) & 1);   // round-to-nearest-even
    return (ushort)(u >> 16);
}
// float -> fp8 e4m3 (OCP on gfx950), single value in byte 0
__device__ __forceinline__ unsigned char f2fp8(float f) {
    return (unsigned char)__builtin_amdgcn_cvt_pk_fp8_f32(f, f, 0, false);
}

// ---------------- setup: convert_x (blocks 0..312) + weight transpose (313..1080) ----------------
__global__ __launch_bounds__(256) void k_setup(const float* __restrict__ x,
                                               ushort* __restrict__ Xp,
                                               const float* __restrict__ W1,
                                               const float* __restrict__ W2,
                                               const float* __restrict__ W3,
                                               ushort* __restrict__ Wt) {
    if (blockIdx.x < 313) {
        // x fp32 row-major -> bf16 chunk planes [c][node][8], LDS transpose
        __shared__ ushort sh[64 * 260];
        int base = blockIdx.x * 64;
        int t = threadIdx.x;
        int col4 = (t & 63) * 4;
#pragma unroll 4
        for (int it = 0; it < 16; ++it) {
            int r = (t >> 6) + it * 4;
            int n = base + r;
            float4 v = (n < N_NODES) ? *(const float4*)(x + (size_t)n * DIM + col4)
                                     : make_float4(0.f, 0.f, 0.f, 0.f);
            ushort4 o; o.x = f2b(v.x); o.y = f2b(v.y); o.z = f2b(v.z); o.w = f2b(v.w);
            *(ushort4*)(sh + r * 260 + col4) = o;
        }
        __syncthreads();
#pragma unroll 4
        for (int it = 0; it < 8; ++it) {
            int q = it * 256 + t;
            int p = q >> 6, nl = q & 63;
            int n = base + nl;
            if (n < N_NODES) {
                uint2 lo = *(uint2*)(sh + nl * 260 + p * 8);
                uint2 hi = *(uint2*)(sh + nl * 260 + p * 8 + 4);
                uint4 o = make_uint4(lo.x, lo.y, hi.x, hi.y);
                *(uint4*)(Xp + (size_t)p * NP16 + (size_t)n * 8) = o;
            }
        }
    } else {
        // Wt[w][n*256+k] = bf16(W_w[k*256+n])
        int i = (blockIdx.x - 313) * 256 + threadIdx.x;   // 0..3*65536-1
        int w = i >> 16, r = i & 65535;
        int n = r >> 8, k = r & 255;
        const float* W = (w == 0) ? W1 : (w == 1) ? W2 : W3;
        Wt[i] = f2b(W[k * 256 + n]);
    }
}

// one pass builds BOTH degree (fill counter) and CSR slots 1..deg (slot 0 = self-loop).
__global__ void k_degfill(const int* __restrict__ src, const int* __restrict__ dst,
                          int* __restrict__ fill, ushort* __restrict__ csr16) {
    int e = blockIdx.x * 256 + threadIdx.x;
    if (e >= N_EDGES) return;
    int s = src[e], d = dst[e];
    int pos = atomicAdd(&fill[d], 1);
    if (pos < SLOT - 1) csr16[d * SLOT + 1 + pos] = (ushort)s;
}

// after k_degfill: dinv, padded row length, self-loop slot, dummy pad slots.
__global__ void k_dinv(const int* __restrict__ fill, float* __restrict__ dinv,
                       int* __restrict__ rlen4, ushort* __restrict__ csr16) {
    int i = blockIdx.x * 256 + threadIdx.x;
    if (i >= N_NODES) return;
    int d = fill[i];
    dinv[i] = rsqrtf((float)d + 1.0f);
    int len = d + 1; if (len > SLOT) len = SLOT;
    int r4 = (len + 3) & ~3;
    rlen4[i] = r4;
    csr16[i * SLOT] = (ushort)i;           // self-loop
    for (int t = len; t < r4; ++t) csr16[i * SLOT + t] = (ushort)DUMMY;
}

// ---------------- gemm phase (device fn): fp8 planes = fp8(dinv[row] * (Xp @ W)) ----------------
// 512-thread block = 2 independent 256-thread gemm groups; grid-stride over 1250 tiles.
__device__ __forceinline__ void gemm_phase(const ushort* __restrict__ Xp,
                                           const ushort* __restrict__ Wt,
                                           const float* __restrict__ dinv,
                                           unsigned char* __restrict__ H8p) {
    int half = threadIdx.x >> 8;         // 0/1
    int t256 = threadIdx.x & 255;
    int wave = t256 >> 6;
    int lane = t256 & 63;
    int rl = lane & 15;
    int kq = (lane >> 4) * 8;
    int n0 = wave * 64;

    for (int t = blockIdx.x * 2 + half; t < NTILE; t += 512) {
        int m0 = t * 16;
        f32x4 acc[4] = {};
#pragma unroll
        for (int kk = 0; kk < 8; ++kk) {
            int k0 = kk * 32;
            int p = (k0 + kq) >> 3;
            bf16x8 a = *(const bf16x8*)(Xp + (size_t)p * NP16 + (size_t)(m0 + rl) * 8);
#pragma unroll
            for (int nb = 0; nb < 4; ++nb) {
                const ushort* bptr = Wt + (size_t)(n0 + nb * 16 + rl) * DIM + k0 + kq;
                bf16x8 b = *(const bf16x8*)bptr;
                acc[nb] = __builtin_amdgcn_mfma_f32_16x16x32_bf16(a, b, acc[nb], 0, 0, 0);
            }
        }
        int crow = m0 + (lane >> 4) * 4;
        float dv0 = dinv[crow], dv1 = dinv[crow + 1], dv2 = dinv[crow + 2], dv3 = dinv[crow + 3];
#pragma unroll
        for (int nb = 0; nb < 4; ++nb) {
            int col = n0 + nb * 16 + rl;
            size_t base = (size_t)(col >> 3) * NP8 + (col & 7);
            H8p[base + (size_t)(crow + 0) * 8] = f2fp8(acc[nb][0] * dv0);
            H8p[base + (size_t)(crow + 1) * 8] = f2fp8(acc[nb][1] * dv1);
            H8p[base + (size_t)(crow + 2) * 8] = f2fp8(acc[nb][2] * dv2);
            H8p[base + (size_t)(crow + 3) * 8] = f2fp8(acc[nb][3] * dv3);
        }
    }
}

// ---------------- agg phase (device fn): LDS-resident fp8 plane, unweighted sum ----------------
__device__ __forceinline__ void agg_phase(unsigned char* lds8,
                                          const unsigned char* __restrict__ H8p,
                                          const int* __restrict__ rlen4,
                                          const ushort* __restrict__ csr16,
                                          const float* __restrict__ dinv,
                                          const float* __restrict__ bias,
                                          const ushort* __restrict__ prevp,
                                          ushort* __restrict__ outp, int mode) {
    int tid = threadIdx.x;
    int c  = blockIdx.x & 31;
    int sl = blockIdx.x >> 5;
    const unsigned char* plane = H8p + (size_t)c * NP8;

    for (int k = tid; k < NP8 / 16; k += CONV_THR)
        ((uint4*)lds8)[k] = ((const uint4*)plane)[k];
    if (tid == 0) *(uint2*)(lds8 + (size_t)DUMMY * 8) = make_uint2(0u, 0u);
    __syncthreads();

    int fo = c * 8;
    float b0 = bias[fo + 0], b1 = bias[fo + 1], b2 = bias[fo + 2], b3 = bias[fo + 3];
    float b4 = bias[fo + 4], b5 = bias[fo + 5], b6 = bias[fo + 6], b7 = bias[fo + 7];

    int dend = sl * 2500 + 2500;
    for (int d = sl * 2500 + tid; d < dend; d += CONV_THR) {
        int rl = rlen4[d];
        const ushort* row = csr16 + (size_t)d * SLOT;
        float a0 = 0.f, a1 = 0.f, a2 = 0.f, a3 = 0.f;
        float a4 = 0.f, a5 = 0.f, a6 = 0.f, a7 = 0.f;
        for (int e = 0; e < rl; e += 4) {
            uint2 m = *(const uint2*)(row + e);
            int i0 = m.x & 0xFFFF, i1 = m.x >> 16;
            int i2 = m.y & 0xFFFF, i3 = m.y >> 16;
            uint2 v0 = *(const uint2*)(lds8 + (size_t)i0 * 8);
            uint2 v1 = *(const uint2*)(lds8 + (size_t)i1 * 8);
            uint2 v2 = *(const uint2*)(lds8 + (size_t)i2 * 8);
            uint2 v3 = *(const uint2*)(lds8 + (size_t)i3 * 8);
            f32x2 lo, hi;
            lo = __builtin_amdgcn_cvt_pk_f32_fp8(v0.x, false);
            hi = __builtin_amdgcn_cvt_pk_f32_fp8(v0.x, true);
            a0 += lo[0]; a1 += lo[1]; a2 += hi[0]; a3 += hi[1];
            lo = __builtin_amdgcn_cvt_pk_f32_fp8(v0.y, false);
            hi = __builtin_amdgcn_cvt_pk_f32_fp8(v0.y, true);
            a4 += lo[0]; a5 += lo[1]; a6 += hi[0]; a7 += hi[1];
            lo = __builtin_amdgcn_cvt_pk_f32_fp8(v1.x, false);
            hi = __builtin_amdgcn_cvt_pk_f32_fp8(v1.x, true);
            a0 += lo[0]; a1 += lo[1]; a2 += hi[0]; a3 += hi[1];
            lo = __builtin_amdgcn_cvt_pk_f32_fp8(v1.y, false);
            hi = __builtin_amdgcn_cvt_pk_f32_fp8(v1.y, true);
            a4 += lo[0]; a5 += lo[1]; a6 += hi[0]; a7 += hi[1];
            lo = __builtin_amdgcn_cvt_pk_f32_fp8(v2.x, false);
            hi = __builtin_amdgcn_cvt_pk_f32_fp8(v2.x, true);
            a0 += lo[0]; a1 += lo[1]; a2 += hi[0]; a3 += hi[1];
            lo = __builtin_amdgcn_cvt_pk_f32_fp8(v2.y, false);
            hi = __builtin_amdgcn_cvt_pk_f32_fp8(v2.y, true);
            a4 += lo[0]; a5 += lo[1]; a6 += hi[0]; a7 += hi[1];
            lo = __builtin_amdgcn_cvt_pk_f32_fp8(v3.x, false);
            hi = __builtin_amdgcn_cvt_pk_f32_fp8(v3.x, true);
            a0 += lo[0]; a1 += lo[1]; a2 += hi[0]; a3 += hi[1];
            lo = __builtin_amdgcn_cvt_pk_f32_fp8(v3.y, false);
            hi = __builtin_amdgcn_cvt_pk_f32_fp8(v3.y, true);
            a4 += lo[0]; a5 += lo[1]; a6 += hi[0]; a7 += hi[1];
        }
        float dv = dinv[d];
        a0 = a0 * dv + b0; a1 = a1 * dv + b1; a2 = a2 * dv + b2; a3 = a3 * dv + b3;
        a4 = a4 * dv + b4; a5 = a5 * dv + b5; a6 = a6 * dv + b6; a7 = a7 * dv + b7;
        if (mode == 1) {
            uint4 pv = *(const uint4*)(prevp + (size_t)c * NP16 + (size_t)d * 8);
            a0 += b2f((ushort)(pv.x & 0xFFFF)); a1 += b2f((ushort)(pv.x >> 16));
            a2 += b2f((ushort)(pv.y & 0xFFFF)); a3 += b2f((ushort)(pv.y >> 16));
            a4 += b2f((ushort)(pv.z & 0xFFFF)); a5 += b2f((ushort)(pv.z >> 16));
            a6 += b2f((ushort)(pv.w & 0xFFFF)); a7 += b2f((ushort)(pv.w >> 16));
        }
        if (mode != 2) {
            a0 = fmaxf(a0, 0.f); a1 = fmaxf(a1, 0.f); a2 = fmaxf(a2, 0.f); a3 = fmaxf(a3, 0.f);
            a4 = fmaxf(a4, 0.f); a5 = fmaxf(a5, 0.f); a6 = fmaxf(a6, 0.f); a7 = fmaxf(a7, 0.f);
        }
        uint4 o;
        o.x = (unsigned)f2b(a0) | ((unsigned)f2b(a1) << 16);
        o.y = (unsigned)f2b(a2) | ((unsigned)f2b(a3) << 16);
        o.z = (unsigned)f2b(a4) | ((unsigned)f2b(a5) << 16);
        o.w = (unsigned)f2b(a6) | ((unsigned)f2b(a7) << 16);
        *(uint4*)(outp + (size_t)c * NP16 + (size_t)d * 8) = o;
    }
}

// ---------------- cooperative conv kernel: 3x (gemm ; sync ; agg ; sync) ----------------
// 256 blocks x 512 thr x 160KB LDS = exactly 1 block/CU -> co-residency guaranteed.
// grid.sync() replaces 5 kernel boundaries (R13 post-mortem: ~100us of dispatch overhead).
__global__ __launch_bounds__(CONV_THR, 1) void k_convs(
    ushort* __restrict__ xb, ushort* __restrict__ h1, unsigned char* __restrict__ h8,
    const ushort* __restrict__ Wt, const float* __restrict__ dinv,
    const int* __restrict__ rlen4, const ushort* __restrict__ csr16,
    const float* __restrict__ b1, const float* __restrict__ b2,
    const float* __restrict__ b3) {
    extern __shared__ unsigned char lds8[];
    cg::grid_group grid = cg::this_grid();

    // conv1: h1 = relu(agg(xb @ W1) + b1)
    gemm_phase(xb, Wt, dinv, h8);
    grid.sync();
    agg_phase(lds8, h8, rlen4, csr16, dinv, b1, nullptr, h1, 0);
    grid.sync();
    // conv2: xb = relu(h1 + agg(h1 @ W2) + b2)
    gemm_phase(h1, Wt + 65536, dinv, h8);
    grid.sync();
    agg_phase(lds8, h8, rlen4, csr16, dinv, b2, h1, xb, 1);
    grid.sync();
    // conv3: h1 = agg(xb @ W3) + b3 (no relu)
    gemm_phase(xb, Wt + 131072, dinv, h8);
    grid.sync();
    agg_phase(lds8, h8, rlen4, csr16, dinv, b3, nullptr, h1, 2);
}

// ---------------- fused pool + bounds + head ----------------
__global__ __launch_bounds__(256) void k_poolfinal(const ushort* __restrict__ h3p,
                                                   const int* __restrict__ batch,
                                                   const float* __restrict__ Wc,
                                                   const float* __restrict__ bc,
                                                   float* __restrict__ out) {
    __shared__ float pooled[DIM];
    __shared__ int se[2];
    __shared__ float logits[N_CLASSES];
    int g = blockIdx.x, f = threadIdx.x;
    if (f < 2) {
        int target = g + f;
        int lo = 0, hi = N_NODES;
        while (lo < hi) {
            int mid = (lo + hi) >> 1;
            if (batch[mid] < target) lo = mid + 1; else hi = mid;
        }
        se[f] = lo;
    }
    __syncthreads();
    int start = se[0], end = se[1];
    int p = f >> 3, jj = f & 7;
    const ushort* base = h3p + (size_t)p * NP16 + jj;
    float acc = 0.0f;
    for (int n = start; n < end; ++n) acc += b2f(base[(size_t)n * 8]);
    float inv = 1.0f / fmaxf((float)(end - start), 1.0f);
    pooled[f] = acc * inv;
    __syncthreads();
    if (f < 64) {   // one wave does the head
        int ff = f * 4;
        float p0 = pooled[ff], p1 = pooled[ff + 1], p2 = pooled[ff + 2], p3 = pooled[ff + 3];
        for (int c = 0; c < N_CLASSES; ++c) {
            float part = p0 * Wc[(ff + 0) * N_CLASSES + c] + p1 * Wc[(ff + 1) * N_CLASSES + c]
                       + p2 * Wc[(ff + 2) * N_CLASSES + c] + p3 * Wc[(ff + 3) * N_CLASSES + c];
            for (int s = 32; s > 0; s >>= 1) part += __shfl_down(part, s);
            if (f == 0) logits[c] = part + bc[c];
        }
        if (f == 0) {
            float mx = logits[0];
            for (int c = 1; c < N_CLASSES; ++c) mx = fmaxf(mx, logits[c]);
            float sexp = 0.f;
            for (int c = 0; c < N_CLASSES; ++c) sexp += expf(logits[c] - mx);
            float lse = mx + logf(sexp);
            for (int c = 0; c < N_CLASSES; ++c) {
                out[g * N_CLASSES + c] = logits[c];
                out[N_GRAPHS * N_CLASSES + g * N_CLASSES + c] = logits[c] - lse;
            }
        }
    }
}

// ---------------- launch ----------------
extern "C" void kernel_launch(void* const* d_in, const int* in_sizes, int n_in,
                              void* d_out, int out_size, void* d_ws, size_t ws_size,
                              hipStream_t stream) {
    const float* x    = (const float*)d_in[0];
    const int*   ei   = (const int*)d_in[1];
    const int*   src  = ei;
    const int*   dst  = ei + N_EDGES;
    const int*   batch= (const int*)d_in[2];
    const float* W1 = (const float*)d_in[3]; const float* b1 = (const float*)d_in[4];
    const float* W2 = (const float*)d_in[5]; const float* b2 = (const float*)d_in[6];
    const float* W3 = (const float*)d_in[7]; const float* b3 = (const float*)d_in[8];
    const float* Wc = (const float*)d_in[9]; const float* bc = (const float*)d_in[10];
    float* out = (float*)d_out;

    // allow 160 KB dynamic LDS for the cooperative conv kernel
    hipFuncSetAttribute(reinterpret_cast<const void*>(k_convs),
                        hipFuncAttributeMaxDynamicSharedMemorySize, NP8 + 16);

    char* ws = (char*)d_ws;
    size_t off = 0;
    auto alloc = [&](size_t bytes) -> char* {
        char* p = ws + off;
        off = (off + bytes + 255) & ~(size_t)255;
        return p;
    };
    // ---- zeroed region (one memset) ----
    int*      fill    = (int*)alloc(N_NODES * 4);      // doubles as degree counter
    size_t    zero_bytes = off;
    // ---- uninitialized scratch ----
    ushort* csr16   = (ushort*)alloc((size_t)N_NODES * SLOT * 2);  // 2.56 MB
    float*  dinv    = (float*)alloc(N_NODES * 4);
    int*    rlen4   = (int*)alloc(N_NODES * 4);
    ushort* Wt      = (ushort*)alloc((size_t)3 * 65536 * 2);
    ushort* xb      = (ushort*)alloc((size_t)N_NODES * DIM * 2);   // bf16 planes
    ushort* h1      = (ushort*)alloc((size_t)N_NODES * DIM * 2);   // bf16 planes
    unsigned char* h8 = (unsigned char*)alloc((size_t)N_NODES * DIM);  // fp8 planes

    hipMemsetAsync(d_ws, 0, zero_bytes, stream);

    k_setup<<<1081, 256, 0, stream>>>(x, xb, W1, W2, W3, Wt);
    k_degfill<<<(N_EDGES + 255) / 256, 256, 0, stream>>>(src, dst, fill, csr16);
    k_dinv<<<(N_NODES + 255) / 256, 256, 0, stream>>>(fill, dinv, rlen4, csr16);

    void* args[] = {(void*)&xb, (void*)&h1, (void*)&h8, (void*)&Wt, (void*)&dinv,
                    (void*)&rlen4, (void*)&csr16, (void*)&b1, (void*)&b2, (void*)&b3};
    hipLaunchCooperativeKernel(reinterpret_cast<const void*>(k_convs),
                               dim3(256), dim3(CONV_THR), args, NP8 + 16, stream);

    k_poolfinal<<<N_GRAPHS, 256, 0, stream>>>(h1, batch, Wc, bc, out);
}

// Round 15
// 264.764 us; speedup vs baseline: 1.6823x; 1.6823x over previous
//
#include <hip/hip_runtime.h>
#include <hip/hip_bf16.h>

#define N_NODES   20000
#define N_EDGES   320000
#define DIM       256
#define N_GRAPHS  64
#define N_CLASSES 10
#define N_CH      32                   // feature chunks of 8
#define NP8       (N_NODES * 8)        // bytes per fp8 plane (160000) = LDS stage size
#define NP16      (N_NODES * 8)        // ushorts per bf16 plane (320000 B)
#define AGG_THR   512                  // 8 waves/block
#define SLOT      64                   // fixed CSR slots per node (max deg+1 = 41 << 64)
#define DUMMY     N_NODES              // pad index -> zeroed row in LDS

typedef short  bf16x8 __attribute__((ext_vector_type(8)));
typedef float  f32x4  __attribute__((ext_vector_type(4)));
typedef float  f32x2  __attribute__((ext_vector_type(2)));

__device__ __forceinline__ float b2f(ushort u) {
    return __uint_as_float(((unsigned)u) << 16);
}
__device__ __forceinline__ ushort f2b(float f) {
    unsigned u = __float_as_uint(f);
    u += 0x7FFF + ((u >> 16) & 1);   // round-to-nearest-even
    return (ushort)(u >> 16);
}
// float -> fp8 e4m3 (OCP on gfx950), single value in byte 0
__device__ __forceinline__ unsigned char f2fp8(float f) {
    return (unsigned char)__builtin_amdgcn_cvt_pk_fp8_f32(f, f, 0, false);
}

// ---------------- setup: convert_x (0..312) + weight transpose (313..1080) + zero fill (1081..1100) ----------------
__global__ __launch_bounds__(256) void k_setup(const float* __restrict__ x,
                                               ushort* __restrict__ Xp,
                                               const float* __restrict__ W1,
                                               const float* __restrict__ W2,
                                               const float* __restrict__ W3,
                                               ushort* __restrict__ Wt,
                                               int* __restrict__ fill) {
    if (blockIdx.x < 313) {
        // x fp32 row-major -> bf16 chunk planes [c][node][8], LDS transpose
        __shared__ ushort sh[64 * 260];
        int base = blockIdx.x * 64;
        int t = threadIdx.x;
        int col4 = (t & 63) * 4;
#pragma unroll 4
        for (int it = 0; it < 16; ++it) {
            int r = (t >> 6) + it * 4;
            int n = base + r;
            float4 v = (n < N_NODES) ? *(const float4*)(x + (size_t)n * DIM + col4)
                                     : make_float4(0.f, 0.f, 0.f, 0.f);
            ushort4 o; o.x = f2b(v.x); o.y = f2b(v.y); o.z = f2b(v.z); o.w = f2b(v.w);
            *(ushort4*)(sh + r * 260 + col4) = o;
        }
        __syncthreads();
#pragma unroll 4
        for (int it = 0; it < 8; ++it) {
            int q = it * 256 + t;
            int p = q >> 6, nl = q & 63;
            int n = base + nl;
            if (n < N_NODES) {
                uint2 lo = *(uint2*)(sh + nl * 260 + p * 8);
                uint2 hi = *(uint2*)(sh + nl * 260 + p * 8 + 4);
                uint4 o = make_uint4(lo.x, lo.y, hi.x, hi.y);
                *(uint4*)(Xp + (size_t)p * NP16 + (size_t)n * 8) = o;
            }
        }
    } else if (blockIdx.x < 1081) {
        // Wt[w][n*256+k] = bf16(W_w[k*256+n])
        int i = (blockIdx.x - 313) * 256 + threadIdx.x;   // 0..3*65536-1
        int w = i >> 16, r = i & 65535;
        int n = r >> 8, k = r & 255;
        const float* W = (w == 0) ? W1 : (w == 1) ? W2 : W3;
        Wt[i] = f2b(W[k * 256 + n]);
    } else {
        // zero the fill/degree counters (replaces hipMemsetAsync)
        int i = (blockIdx.x - 1081) * 256 + threadIdx.x;  // 0..5119, need 5000 int4
        if (i < N_NODES / 4) ((int4*)fill)[i] = make_int4(0, 0, 0, 0);
    }
}

// one pass builds BOTH degree (fill counter) and CSR slots 1..deg (slot 0 = self-loop).
__global__ void k_degfill(const int* __restrict__ src, const int* __restrict__ dst,
                          int* __restrict__ fill, ushort* __restrict__ csr16) {
    int e = blockIdx.x * 256 + threadIdx.x;
    if (e >= N_EDGES) return;
    int s = src[e], d = dst[e];
    int pos = atomicAdd(&fill[d], 1);
    if (pos < SLOT - 1) csr16[d * SLOT + 1 + pos] = (ushort)s;
}

// after k_degfill: dinv, padded row length, self-loop slot, dummy pad slots.
__global__ void k_dinv(const int* __restrict__ fill, float* __restrict__ dinv,
                       int* __restrict__ rlen4, ushort* __restrict__ csr16) {
    int i = blockIdx.x * 256 + threadIdx.x;
    if (i >= N_NODES) return;
    int d = fill[i];
    dinv[i] = rsqrtf((float)d + 1.0f);
    int len = d + 1; if (len > SLOT) len = SLOT;
    int r4 = (len + 3) & ~3;
    rlen4[i] = r4;
    csr16[i * SLOT] = (ushort)i;           // self-loop
    for (int t = len; t < r4; ++t) csr16[i * SLOT + t] = (ushort)DUMMY;
}

// ---------------- GEMM: fp8 planes = fp8(dinv[row] * (Xp @ W)), 2 tiles/block ----------------
// Block = 256 thr handles 32 rows (two 16-row MFMA tiles sharing B-fragments):
// halves Wt L2 traffic (160->80 MB/conv) and doubles MFMA per load.
__global__ __launch_bounds__(256) void k_gemm(const ushort* __restrict__ Xp,
                                              const ushort* __restrict__ Wt,
                                              const float* __restrict__ dinv,
                                              unsigned char* __restrict__ H8p) {
    int wave = threadIdx.x >> 6;
    int lane = threadIdx.x & 63;
    int m0 = blockIdx.x * 32;            // 625 blocks
    int n0 = wave * 64;
    int rl = lane & 15;
    int kq = (lane >> 4) * 8;

    f32x4 acc0[4] = {}, acc1[4] = {};

#pragma unroll
    for (int kk = 0; kk < 8; ++kk) {
        int k0 = kk * 32;
        int p = (k0 + kq) >> 3;
        const ushort* xp = Xp + (size_t)p * NP16;
        bf16x8 a0 = *(const bf16x8*)(xp + (size_t)(m0 + rl) * 8);
        bf16x8 a1 = *(const bf16x8*)(xp + (size_t)(m0 + 16 + rl) * 8);
#pragma unroll
        for (int nb = 0; nb < 4; ++nb) {
            const ushort* bptr = Wt + (size_t)(n0 + nb * 16 + rl) * DIM + k0 + kq;
            bf16x8 b = *(const bf16x8*)bptr;
            acc0[nb] = __builtin_amdgcn_mfma_f32_16x16x32_bf16(a0, b, acc0[nb], 0, 0, 0);
            acc1[nb] = __builtin_amdgcn_mfma_f32_16x16x32_bf16(a1, b, acc1[nb], 0, 0, 0);
        }
    }
    int crow0 = m0 + (lane >> 4) * 4;
    int crow1 = crow0 + 16;
    float d00 = dinv[crow0], d01 = dinv[crow0 + 1], d02 = dinv[crow0 + 2], d03 = dinv[crow0 + 3];
    float d10 = dinv[crow1], d11 = dinv[crow1 + 1], d12 = dinv[crow1 + 2], d13 = dinv[crow1 + 3];
#pragma unroll
    for (int nb = 0; nb < 4; ++nb) {
        int col = n0 + nb * 16 + rl;
        size_t base = (size_t)(col >> 3) * NP8 + (col & 7);
        H8p[base + (size_t)(crow0 + 0) * 8] = f2fp8(acc0[nb][0] * d00);
        H8p[base + (size_t)(crow0 + 1) * 8] = f2fp8(acc0[nb][1] * d01);
        H8p[base + (size_t)(crow0 + 2) * 8] = f2fp8(acc0[nb][2] * d02);
        H8p[base + (size_t)(crow0 + 3) * 8] = f2fp8(acc0[nb][3] * d03);
        H8p[base + (size_t)(crow1 + 0) * 8] = f2fp8(acc1[nb][0] * d10);
        H8p[base + (size_t)(crow1 + 1) * 8] = f2fp8(acc1[nb][1] * d11);
        H8p[base + (size_t)(crow1 + 2) * 8] = f2fp8(acc1[nb][2] * d12);
        H8p[base + (size_t)(crow1 + 3) * 8] = f2fp8(acc1[nb][3] * d13);
    }
}

// ---------------- aggregation: LDS-resident fp8 plane, unweighted sum (R13-proven) ----------------
__global__ __launch_bounds__(AGG_THR, 1) void k_agg(
    const unsigned char* __restrict__ H8p, const int* __restrict__ rlen4,
    const ushort* __restrict__ csr16, const float* __restrict__ dinv,
    const float* __restrict__ bias, const ushort* __restrict__ prevp,
    ushort* __restrict__ outp, int mode) {
    extern __shared__ unsigned char lds8[];      // 160016 B: [node][8] fp8 + dummy row
    int tid = threadIdx.x;
    int c  = blockIdx.x & 31;                    // chunk
    int sl = blockIdx.x >> 5;                    // dst slice
    const unsigned char* plane = H8p + (size_t)c * NP8;

    for (int k = tid; k < NP8 / 16; k += AGG_THR)
        ((uint4*)lds8)[k] = ((const uint4*)plane)[k];
    if (tid == 0) *(uint2*)(lds8 + (size_t)DUMMY * 8) = make_uint2(0u, 0u);
    __syncthreads();

    int fo = c * 8;
    float b0 = bias[fo + 0], b1 = bias[fo + 1], b2 = bias[fo + 2], b3 = bias[fo + 3];
    float b4 = bias[fo + 4], b5 = bias[fo + 5], b6 = bias[fo + 6], b7 = bias[fo + 7];

    int dend = sl * 2500 + 2500;
    for (int d = sl * 2500 + tid; d < dend; d += AGG_THR) {
        int rl = rlen4[d];
        const ushort* row = csr16 + (size_t)d * SLOT;
        float a0 = 0.f, a1 = 0.f, a2 = 0.f, a3 = 0.f;
        float a4 = 0.f, a5 = 0.f, a6 = 0.f, a7 = 0.f;
        for (int e = 0; e < rl; e += 4) {
            uint2 m = *(const uint2*)(row + e);
            int i0 = m.x & 0xFFFF, i1 = m.x >> 16;
            int i2 = m.y & 0xFFFF, i3 = m.y >> 16;
            uint2 v0 = *(const uint2*)(lds8 + (size_t)i0 * 8);
            uint2 v1 = *(const uint2*)(lds8 + (size_t)i1 * 8);
            uint2 v2 = *(const uint2*)(lds8 + (size_t)i2 * 8);
            uint2 v3 = *(const uint2*)(lds8 + (size_t)i3 * 8);
            f32x2 lo, hi;
            lo = __builtin_amdgcn_cvt_pk_f32_fp8(v0.x, false);
            hi = __builtin_amdgcn_cvt_pk_f32_fp8(v0.x, true);
            a0 += lo[0]; a1 += lo[1]; a2 += hi[0]; a3 += hi[1];
            lo = __builtin_amdgcn_cvt_pk_f32_fp8(v0.y, false);
            hi = __builtin_amdgcn_cvt_pk_f32_fp8(v0.y, true);
            a4 += lo[0]; a5 += lo[1]; a6 += hi[0]; a7 += hi[1];
            lo = __builtin_amdgcn_cvt_pk_f32_fp8(v1.x, false);
            hi = __builtin_amdgcn_cvt_pk_f32_fp8(v1.x, true);
            a0 += lo[0]; a1 += lo[1]; a2 += hi[0]; a3 += hi[1];
            lo = __builtin_amdgcn_cvt_pk_f32_fp8(v1.y, false);
            hi = __builtin_amdgcn_cvt_pk_f32_fp8(v1.y, true);
            a4 += lo[0]; a5 += lo[1]; a6 += hi[0]; a7 += hi[1];
            lo = __builtin_amdgcn_cvt_pk_f32_fp8(v2.x, false);
            hi = __builtin_amdgcn_cvt_pk_f32_fp8(v2.x, true);
            a0 += lo[0]; a1 += lo[1]; a2 += hi[0]; a3 += hi[1];
            lo = __builtin_amdgcn_cvt_pk_f32_fp8(v2.y, false);
            hi = __builtin_amdgcn_cvt_pk_f32_fp8(v2.y, true);
            a4 += lo[0]; a5 += lo[1]; a6 += hi[0]; a7 += hi[1];
            lo = __builtin_amdgcn_cvt_pk_f32_fp8(v3.x, false);
            hi = __builtin_amdgcn_cvt_pk_f32_fp8(v3.x, true);
            a0 += lo[0]; a1 += lo[1]; a2 += hi[0]; a3 += hi[1];
            lo = __builtin_amdgcn_cvt_pk_f32_fp8(v3.y, false);
            hi = __builtin_amdgcn_cvt_pk_f32_fp8(v3.y, true);
            a4 += lo[0]; a5 += lo[1]; a6 += hi[0]; a7 += hi[1];
        }
        float dv = dinv[d];
        a0 = a0 * dv + b0; a1 = a1 * dv + b1; a2 = a2 * dv + b2; a3 = a3 * dv + b3;
        a4 = a4 * dv + b4; a5 = a5 * dv + b5; a6 = a6 * dv + b6; a7 = a7 * dv + b7;
        if (mode == 1) {
            uint4 pv = *(const uint4*)(prevp + (size_t)c * NP16 + (size_t)d * 8);
            a0 += b2f((ushort)(pv.x & 0xFFFF)); a1 += b2f((ushort)(pv.x >> 16));
            a2 += b2f((ushort)(pv.y & 0xFFFF)); a3 += b2f((ushort)(pv.y >> 16));
            a4 += b2f((ushort)(pv.z & 0xFFFF)); a5 += b2f((ushort)(pv.z >> 16));
            a6 += b2f((ushort)(pv.w & 0xFFFF)); a7 += b2f((ushort)(pv.w >> 16));
        }
        if (mode != 2) {
            a0 = fmaxf(a0, 0.f); a1 = fmaxf(a1, 0.f); a2 = fmaxf(a2, 0.f); a3 = fmaxf(a3, 0.f);
            a4 = fmaxf(a4, 0.f); a5 = fmaxf(a5, 0.f); a6 = fmaxf(a6, 0.f); a7 = fmaxf(a7, 0.f);
        }
        uint4 o;
        o.x = (unsigned)f2b(a0) | ((unsigned)f2b(a1) << 16);
        o.y = (unsigned)f2b(a2) | ((unsigned)f2b(a3) << 16);
        o.z = (unsigned)f2b(a4) | ((unsigned)f2b(a5) << 16);
        o.w = (unsigned)f2b(a6) | ((unsigned)f2b(a7) << 16);
        *(uint4*)(outp + (size_t)c * NP16 + (size_t)d * 8) = o;
    }
}

// ---------------- fused pool + bounds + head (512 thr: 2-way parallel node sum) ----------------
__global__ __launch_bounds__(512) void k_poolfinal(const ushort* __restrict__ h3p,
                                                   const int* __restrict__ batch,
                                                   const float* __restrict__ Wc,
                                                   const float* __restrict__ bc,
                                                   float* __restrict__ out) {
    __shared__ float part[2][DIM];
    __shared__ int se[2];
    __shared__ float logits[N_CLASSES];
    int g = blockIdx.x, tid = threadIdx.x;
    int f = tid & 255, h = tid >> 8;
    if (tid < 2) {
        int target = g + tid;
        int lo = 0, hi = N_NODES;
        while (lo < hi) {
            int mid = (lo + hi) >> 1;
            if (batch[mid] < target) lo = mid + 1; else hi = mid;
        }
        se[tid] = lo;
    }
    __syncthreads();
    int start = se[0], end = se[1];
    int mid = (start + end) >> 1;
    int s = h ? mid : start, e = h ? end : mid;
    int p = f >> 3, jj = f & 7;
    const ushort* base = h3p + (size_t)p * NP16 + jj;
    float acc = 0.0f;
    for (int n = s; n < e; ++n) acc += b2f(base[(size_t)n * 8]);
    part[h][f] = acc;
    __syncthreads();
    if (tid < DIM) {
        float inv = 1.0f / fmaxf((float)(end - start), 1.0f);
        part[0][tid] = (part[0][tid] + part[1][tid]) * inv;
    }
    __syncthreads();
    if (tid < 64) {   // one wave does the head
        int ff = tid * 4;
        float p0 = part[0][ff], p1 = part[0][ff + 1], p2 = part[0][ff + 2], p3 = part[0][ff + 3];
        for (int c = 0; c < N_CLASSES; ++c) {
            float pr = p0 * Wc[(ff + 0) * N_CLASSES + c] + p1 * Wc[(ff + 1) * N_CLASSES + c]
                     + p2 * Wc[(ff + 2) * N_CLASSES + c] + p3 * Wc[(ff + 3) * N_CLASSES + c];
            for (int st = 32; st > 0; st >>= 1) pr += __shfl_down(pr, st);
            if (tid == 0) logits[c] = pr + bc[c];
        }
        if (tid == 0) {
            float mx = logits[0];
            for (int c = 1; c < N_CLASSES; ++c) mx = fmaxf(mx, logits[c]);
            float sexp = 0.f;
            for (int c = 0; c < N_CLASSES; ++c) sexp += expf(logits[c] - mx);
            float lse = mx + logf(sexp);
            for (int c = 0; c < N_CLASSES; ++c) {
                out[g * N_CLASSES + c] = logits[c];
                out[N_GRAPHS * N_CLASSES + g * N_CLASSES + c] = logits[c] - lse;
            }
        }
    }
}

// ---------------- launch ----------------
extern "C" void kernel_launch(void* const* d_in, const int* in_sizes, int n_in,
                              void* d_out, int out_size, void* d_ws, size_t ws_size,
                              hipStream_t stream) {
    const float* x    = (const float*)d_in[0];
    const int*   ei   = (const int*)d_in[1];
    const int*   src  = ei;
    const int*   dst  = ei + N_EDGES;
    const int*   batch= (const int*)d_in[2];
    const float* W1 = (const float*)d_in[3]; const float* b1 = (const float*)d_in[4];
    const float* W2 = (const float*)d_in[5]; const float* b2 = (const float*)d_in[6];
    const float* W3 = (const float*)d_in[7]; const float* b3 = (const float*)d_in[8];
    const float* Wc = (const float*)d_in[9]; const float* bc = (const float*)d_in[10];
    float* out = (float*)d_out;

    // allow 160 KB dynamic LDS for k_agg (idempotent, capture-safe)
    hipFuncSetAttribute(reinterpret_cast<const void*>(k_agg),
                        hipFuncAttributeMaxDynamicSharedMemorySize, NP8 + 16);

    char* ws = (char*)d_ws;
    size_t off = 0;
    auto alloc = [&](size_t bytes) -> char* {
        char* p = ws + off;
        off = (off + bytes + 255) & ~(size_t)255;
        return p;
    };
    int*    fill    = (int*)alloc(N_NODES * 4);      // zeroed by k_setup
    ushort* csr16   = (ushort*)alloc((size_t)N_NODES * SLOT * 2);  // 2.56 MB
    float*  dinv    = (float*)alloc(N_NODES * 4);
    int*    rlen4   = (int*)alloc(N_NODES * 4);
    ushort* Wt      = (ushort*)alloc((size_t)3 * 65536 * 2);
    ushort* xb      = (ushort*)alloc((size_t)N_NODES * DIM * 2);   // bf16 planes
    ushort* h1      = (ushort*)alloc((size_t)N_NODES * DIM * 2);   // bf16 planes
    unsigned char* h8 = (unsigned char*)alloc((size_t)N_NODES * DIM);  // fp8 planes

    k_setup<<<1101, 256, 0, stream>>>(x, xb, W1, W2, W3, Wt, fill);
    k_degfill<<<(N_EDGES + 255) / 256, 256, 0, stream>>>(src, dst, fill, csr16);
    k_dinv<<<(N_NODES + 255) / 256, 256, 0, stream>>>(fill, dinv, rlen4, csr16);

    const int agg_grid = N_CH * 8;         // 256 blocks, 1/CU, 160 KB LDS, 512 thr
    const int gemm_grid = N_NODES / 32;    // 625 blocks, 2 tiles each

    // conv1: h1 = relu(agg(xb @ W1) + b1)
    k_gemm<<<gemm_grid, 256, 0, stream>>>(xb, Wt, dinv, h8);
    k_agg<<<agg_grid, AGG_THR, NP8 + 16, stream>>>(h8, rlen4, csr16, dinv, b1, nullptr, h1, 0);
    // conv2: xb = relu(h1 + agg(h1 @ W2) + b2)
    k_gemm<<<gemm_grid, 256, 0, stream>>>(h1, Wt + 65536, dinv, h8);
    k_agg<<<agg_grid, AGG_THR, NP8 + 16, stream>>>(h8, rlen4, csr16, dinv, b2, h1, xb, 1);
    // conv3: h1 = agg(xb @ W3) + b3 (no relu), then pool
    k_gemm<<<gemm_grid, 256, 0, stream>>>(xb, Wt + 131072, dinv, h8);
    k_agg<<<agg_grid, AGG_THR, NP8 + 16, stream>>>(h8, rlen4, csr16, dinv, b3, nullptr, h1, 2);

    k_poolfinal<<<N_GRAPHS, 512, 0, stream>>>(h1, batch, Wc, bc, out);
}

// Round 16
// 246.446 us; speedup vs baseline: 1.8073x; 1.0743x over previous
//
#include <hip/hip_runtime.h>
#include <hip/hip_bf16.h>

#define N_NODES   20000
#define N_EDGES   320000
#define DIM       256
#define N_GRAPHS  64
#define N_CLASSES 10
#define N_CH      32                   // feature chunks of 8
#define NP8       (N_NODES * 8)        // bytes per fp8 plane (160000) = LDS stage size
#define NP16      (N_NODES * 8)        // ushorts per bf16 plane (320000 B)
#define AGG_THR   512                  // 8 waves/block
#define SLOT      64                   // fixed CSR slots per node (max deg+1 = 41 << 64)
#define DUMMY     N_NODES              // pad index -> zeroed row in LDS

typedef short  bf16x8 __attribute__((ext_vector_type(8)));
typedef float  f32x4  __attribute__((ext_vector_type(4)));
typedef float  f32x2  __attribute__((ext_vector_type(2)));

__device__ __forceinline__ float b2f(ushort u) {
    return __uint_as_float(((unsigned)u) << 16);
}
__device__ __forceinline__ ushort f2b(float f) {
    unsigned u = __float_as_uint(f);
    u += 0x7FFF + ((u >> 16) & 1);   // round-to-nearest-even
    return (ushort)(u >> 16);
}
// float -> fp8 e4m3 (OCP on gfx950), single value in byte 0
__device__ __forceinline__ unsigned char f2fp8(float f) {
    return (unsigned char)__builtin_amdgcn_cvt_pk_fp8_f32(f, f, 0, false);
}

// ---------------- setup: convert_x (0..312) + weight transpose (313..1080) + zero fill (1081..1100) ----------------
__global__ __launch_bounds__(256) void k_setup(const float* __restrict__ x,
                                               ushort* __restrict__ Xp,
                                               const float* __restrict__ W1,
                                               const float* __restrict__ W2,
                                               const float* __restrict__ W3,
                                               ushort* __restrict__ Wt,
                                               int* __restrict__ fill) {
    if (blockIdx.x < 313) {
        // x fp32 row-major -> bf16 chunk planes [c][node][8], LDS transpose
        __shared__ ushort sh[64 * 260];
        int base = blockIdx.x * 64;
        int t = threadIdx.x;
        int col4 = (t & 63) * 4;
#pragma unroll 4
        for (int it = 0; it < 16; ++it) {
            int r = (t >> 6) + it * 4;
            int n = base + r;
            float4 v = (n < N_NODES) ? *(const float4*)(x + (size_t)n * DIM + col4)
                                     : make_float4(0.f, 0.f, 0.f, 0.f);
            ushort4 o; o.x = f2b(v.x); o.y = f2b(v.y); o.z = f2b(v.z); o.w = f2b(v.w);
            *(ushort4*)(sh + r * 260 + col4) = o;
        }
        __syncthreads();
#pragma unroll 4
        for (int it = 0; it < 8; ++it) {
            int q = it * 256 + t;
            int p = q >> 6, nl = q & 63;
            int n = base + nl;
            if (n < N_NODES) {
                uint2 lo = *(uint2*)(sh + nl * 260 + p * 8);
                uint2 hi = *(uint2*)(sh + nl * 260 + p * 8 + 4);
                uint4 o = make_uint4(lo.x, lo.y, hi.x, hi.y);
                *(uint4*)(Xp + (size_t)p * NP16 + (size_t)n * 8) = o;
            }
        }
    } else if (blockIdx.x < 1081) {
        // Wt[w][n*256+k] = bf16(W_w[k*256+n])
        int i = (blockIdx.x - 313) * 256 + threadIdx.x;   // 0..3*65536-1
        int w = i >> 16, r = i & 65535;
        int n = r >> 8, k = r & 255;
        const float* W = (w == 0) ? W1 : (w == 1) ? W2 : W3;
        Wt[i] = f2b(W[k * 256 + n]);
    } else {
        // zero the fill/degree counters (replaces hipMemsetAsync)
        int i = (blockIdx.x - 1081) * 256 + threadIdx.x;  // 0..5119, need 5000 int4
        if (i < N_NODES / 4) ((int4*)fill)[i] = make_int4(0, 0, 0, 0);
    }
}

// one pass builds BOTH degree (fill counter) and CSR slots 1..deg (slot 0 = self-loop).
__global__ void k_degfill(const int* __restrict__ src, const int* __restrict__ dst,
                          int* __restrict__ fill, ushort* __restrict__ csr16) {
    int e = blockIdx.x * 256 + threadIdx.x;
    if (e >= N_EDGES) return;
    int s = src[e], d = dst[e];
    int pos = atomicAdd(&fill[d], 1);
    if (pos < SLOT - 1) csr16[d * SLOT + 1 + pos] = (ushort)s;
}

// after k_degfill: dinv, padded row length, self-loop slot, dummy pad slots.
__global__ void k_dinv(const int* __restrict__ fill, float* __restrict__ dinv,
                       int* __restrict__ rlen4, ushort* __restrict__ csr16) {
    int i = blockIdx.x * 256 + threadIdx.x;
    if (i >= N_NODES) return;
    int d = fill[i];
    dinv[i] = rsqrtf((float)d + 1.0f);
    int len = d + 1; if (len > SLOT) len = SLOT;
    int r4 = (len + 3) & ~3;
    rlen4[i] = r4;
    csr16[i * SLOT] = (ushort)i;           // self-loop
    for (int t = len; t < r4; ++t) csr16[i * SLOT + t] = (ushort)DUMMY;
}

// ---------------- GEMM: fp8 planes = fp8(dinv[row] * (Xp @ W)), 2 tiles/block ----------------
__global__ __launch_bounds__(256) void k_gemm(const ushort* __restrict__ Xp,
                                              const ushort* __restrict__ Wt,
                                              const float* __restrict__ dinv,
                                              unsigned char* __restrict__ H8p) {
    int wave = threadIdx.x >> 6;
    int lane = threadIdx.x & 63;
    int m0 = blockIdx.x * 32;            // 625 blocks
    int n0 = wave * 64;
    int rl = lane & 15;
    int kq = (lane >> 4) * 8;

    f32x4 acc0[4] = {}, acc1[4] = {};

#pragma unroll
    for (int kk = 0; kk < 8; ++kk) {
        int k0 = kk * 32;
        int p = (k0 + kq) >> 3;
        const ushort* xp = Xp + (size_t)p * NP16;
        bf16x8 a0 = *(const bf16x8*)(xp + (size_t)(m0 + rl) * 8);
        bf16x8 a1 = *(const bf16x8*)(xp + (size_t)(m0 + 16 + rl) * 8);
#pragma unroll
        for (int nb = 0; nb < 4; ++nb) {
            const ushort* bptr = Wt + (size_t)(n0 + nb * 16 + rl) * DIM + k0 + kq;
            bf16x8 b = *(const bf16x8*)bptr;
            acc0[nb] = __builtin_amdgcn_mfma_f32_16x16x32_bf16(a0, b, acc0[nb], 0, 0, 0);
            acc1[nb] = __builtin_amdgcn_mfma_f32_16x16x32_bf16(a1, b, acc1[nb], 0, 0, 0);
        }
    }
    int crow0 = m0 + (lane >> 4) * 4;
    int crow1 = crow0 + 16;
    float d00 = dinv[crow0], d01 = dinv[crow0 + 1], d02 = dinv[crow0 + 2], d03 = dinv[crow0 + 3];
    float d10 = dinv[crow1], d11 = dinv[crow1 + 1], d12 = dinv[crow1 + 2], d13 = dinv[crow1 + 3];
#pragma unroll
    for (int nb = 0; nb < 4; ++nb) {
        int col = n0 + nb * 16 + rl;
        size_t base = (size_t)(col >> 3) * NP8 + (col & 7);
        H8p[base + (size_t)(crow0 + 0) * 8] = f2fp8(acc0[nb][0] * d00);
        H8p[base + (size_t)(crow0 + 1) * 8] = f2fp8(acc0[nb][1] * d01);
        H8p[base + (size_t)(crow0 + 2) * 8] = f2fp8(acc0[nb][2] * d02);
        H8p[base + (size_t)(crow0 + 3) * 8] = f2fp8(acc0[nb][3] * d03);
        H8p[base + (size_t)(crow1 + 0) * 8] = f2fp8(acc1[nb][0] * d10);
        H8p[base + (size_t)(crow1 + 1) * 8] = f2fp8(acc1[nb][1] * d11);
        H8p[base + (size_t)(crow1 + 2) * 8] = f2fp8(acc1[nb][2] * d12);
        H8p[base + (size_t)(crow1 + 3) * 8] = f2fp8(acc1[nb][3] * d13);
    }
}

// ---------------- aggregation: LDS-resident fp8 plane, unweighted sum (R13-proven) ----------------
__global__ __launch_bounds__(AGG_THR, 1) void k_agg(
    const unsigned char* __restrict__ H8p, const int* __restrict__ rlen4,
    const ushort* __restrict__ csr16, const float* __restrict__ dinv,
    const float* __restrict__ bias, const ushort* __restrict__ prevp,
    ushort* __restrict__ outp, int mode) {
    extern __shared__ unsigned char lds8[];      // 160016 B: [node][8] fp8 + dummy row
    int tid = threadIdx.x;
    int c  = blockIdx.x & 31;                    // chunk
    int sl = blockIdx.x >> 5;                    // dst slice
    const unsigned char* plane = H8p + (size_t)c * NP8;

    for (int k = tid; k < NP8 / 16; k += AGG_THR)
        ((uint4*)lds8)[k] = ((const uint4*)plane)[k];
    if (tid == 0) *(uint2*)(lds8 + (size_t)DUMMY * 8) = make_uint2(0u, 0u);
    __syncthreads();

    int fo = c * 8;
    float b0 = bias[fo + 0], b1 = bias[fo + 1], b2 = bias[fo + 2], b3 = bias[fo + 3];
    float b4 = bias[fo + 4], b5 = bias[fo + 5], b6 = bias[fo + 6], b7 = bias[fo + 7];

    int dend = sl * 2500 + 2500;
    for (int d = sl * 2500 + tid; d < dend; d += AGG_THR) {
        int rl = rlen4[d];
        const ushort* row = csr16 + (size_t)d * SLOT;
        float a0 = 0.f, a1 = 0.f, a2 = 0.f, a3 = 0.f;
        float a4 = 0.f, a5 = 0.f, a6 = 0.f, a7 = 0.f;
        for (int e = 0; e < rl; e += 4) {
            uint2 m = *(const uint2*)(row + e);
            int i0 = m.x & 0xFFFF, i1 = m.x >> 16;
            int i2 = m.y & 0xFFFF, i3 = m.y >> 16;
            uint2 v0 = *(const uint2*)(lds8 + (size_t)i0 * 8);
            uint2 v1 = *(const uint2*)(lds8 + (size_t)i1 * 8);
            uint2 v2 = *(const uint2*)(lds8 + (size_t)i2 * 8);
            uint2 v3 = *(const uint2*)(lds8 + (size_t)i3 * 8);
            f32x2 lo, hi;
            lo = __builtin_amdgcn_cvt_pk_f32_fp8(v0.x, false);
            hi = __builtin_amdgcn_cvt_pk_f32_fp8(v0.x, true);
            a0 += lo[0]; a1 += lo[1]; a2 += hi[0]; a3 += hi[1];
            lo = __builtin_amdgcn_cvt_pk_f32_fp8(v0.y, false);
            hi = __builtin_amdgcn_cvt_pk_f32_fp8(v0.y, true);
            a4 += lo[0]; a5 += lo[1]; a6 += hi[0]; a7 += hi[1];
            lo = __builtin_amdgcn_cvt_pk_f32_fp8(v1.x, false);
            hi = __builtin_amdgcn_cvt_pk_f32_fp8(v1.x, true);
            a0 += lo[0]; a1 += lo[1]; a2 += hi[0]; a3 += hi[1];
            lo = __builtin_amdgcn_cvt_pk_f32_fp8(v1.y, false);
            hi = __builtin_amdgcn_cvt_pk_f32_fp8(v1.y, true);
            a4 += lo[0]; a5 += lo[1]; a6 += hi[0]; a7 += hi[1];
            lo = __builtin_amdgcn_cvt_pk_f32_fp8(v2.x, false);
            hi = __builtin_amdgcn_cvt_pk_f32_fp8(v2.x, true);
            a0 += lo[0]; a1 += lo[1]; a2 += hi[0]; a3 += hi[1];
            lo = __builtin_amdgcn_cvt_pk_f32_fp8(v2.y, false);
            hi = __builtin_amdgcn_cvt_pk_f32_fp8(v2.y, true);
            a4 += lo[0]; a5 += lo[1]; a6 += hi[0]; a7 += hi[1];
            lo = __builtin_amdgcn_cvt_pk_f32_fp8(v3.x, false);
            hi = __builtin_amdgcn_cvt_pk_f32_fp8(v3.x, true);
            a0 += lo[0]; a1 += lo[1]; a2 += hi[0]; a3 += hi[1];
            lo = __builtin_amdgcn_cvt_pk_f32_fp8(v3.y, false);
            hi = __builtin_amdgcn_cvt_pk_f32_fp8(v3.y, true);
            a4 += lo[0]; a5 += lo[1]; a6 += hi[0]; a7 += hi[1];
        }
        float dv = dinv[d];
        a0 = a0 * dv + b0; a1 = a1 * dv + b1; a2 = a2 * dv + b2; a3 = a3 * dv + b3;
        a4 = a4 * dv + b4; a5 = a5 * dv + b5; a6 = a6 * dv + b6; a7 = a7 * dv + b7;
        if (mode == 1) {
            uint4 pv = *(const uint4*)(prevp + (size_t)c * NP16 + (size_t)d * 8);
            a0 += b2f((ushort)(pv.x & 0xFFFF)); a1 += b2f((ushort)(pv.x >> 16));
            a2 += b2f((ushort)(pv.y & 0xFFFF)); a3 += b2f((ushort)(pv.y >> 16));
            a4 += b2f((ushort)(pv.z & 0xFFFF)); a5 += b2f((ushort)(pv.z >> 16));
            a6 += b2f((ushort)(pv.w & 0xFFFF)); a7 += b2f((ushort)(pv.w >> 16));
        }
        if (mode != 2) {
            a0 = fmaxf(a0, 0.f); a1 = fmaxf(a1, 0.f); a2 = fmaxf(a2, 0.f); a3 = fmaxf(a3, 0.f);
            a4 = fmaxf(a4, 0.f); a5 = fmaxf(a5, 0.f); a6 = fmaxf(a6, 0.f); a7 = fmaxf(a7, 0.f);
        }
        uint4 o;
        o.x = (unsigned)f2b(a0) | ((unsigned)f2b(a1) << 16);
        o.y = (unsigned)f2b(a2) | ((unsigned)f2b(a3) << 16);
        o.z = (unsigned)f2b(a4) | ((unsigned)f2b(a5) << 16);
        o.w = (unsigned)f2b(a6) | ((unsigned)f2b(a7) << 16);
        *(uint4*)(outp + (size_t)c * NP16 + (size_t)d * 8) = o;
    }
}

// ---------------- fused pool + bounds + head (vectorized: uint4 per node-plane) ----------------
// R15 post-mortem: scalar 2B loads + 64 blocks = 43.6us latency-bound. Now thread =
// (plane c = tid>>4, stride-slot q = tid&15): uint4 load (8 features) per node,
// ~20 iterations; 16-way LDS reduce -> pooled[256]; one wave does the head.
__global__ __launch_bounds__(512) void k_poolfinal(const ushort* __restrict__ h3p,
                                                   const int* __restrict__ batch,
                                                   const float* __restrict__ Wc,
                                                   const float* __restrict__ bc,
                                                   float* __restrict__ out) {
    __shared__ float part[512 * 8];          // 16 KB
    __shared__ float pooled[DIM];
    __shared__ int se[2];
    __shared__ float logits[N_CLASSES];
    int g = blockIdx.x, tid = threadIdx.x;
    int c = tid >> 4;                        // plane 0..31
    int q = tid & 15;                        // node stride slot
    if (tid < 2) {
        int target = g + tid;
        int lo = 0, hi = N_NODES;
        while (lo < hi) {
            int mid = (lo + hi) >> 1;
            if (batch[mid] < target) lo = mid + 1; else hi = mid;
        }
        se[tid] = lo;
    }
    __syncthreads();
    int start = se[0], end = se[1];
    float a[8] = {};
    const ushort* pb = h3p + (size_t)c * NP16;
    for (int n = start + q; n < end; n += 16) {
        uint4 v = *(const uint4*)(pb + (size_t)n * 8);
        a[0] += b2f((ushort)(v.x & 0xFFFF)); a[1] += b2f((ushort)(v.x >> 16));
        a[2] += b2f((ushort)(v.y & 0xFFFF)); a[3] += b2f((ushort)(v.y >> 16));
        a[4] += b2f((ushort)(v.z & 0xFFFF)); a[5] += b2f((ushort)(v.z >> 16));
        a[6] += b2f((ushort)(v.w & 0xFFFF)); a[7] += b2f((ushort)(v.w >> 16));
    }
#pragma unroll
    for (int j = 0; j < 8; ++j) part[tid * 8 + j] = a[j];
    __syncthreads();
    if (tid < DIM) {                         // feature f = tid; c = f>>3, j = f&7
        int cc = tid >> 3, jj = tid & 7;
        float s = 0.0f;
#pragma unroll 4
        for (int q2 = 0; q2 < 16; ++q2) s += part[(cc * 16 + q2) * 8 + jj];
        float inv = 1.0f / fmaxf((float)(end - start), 1.0f);
        pooled[tid] = s * inv;
    }
    __syncthreads();
    if (tid < 64) {   // one wave does the head
        int ff = tid * 4;
        float p0 = pooled[ff], p1 = pooled[ff + 1], p2 = pooled[ff + 2], p3 = pooled[ff + 3];
        for (int cl = 0; cl < N_CLASSES; ++cl) {
            float pr = p0 * Wc[(ff + 0) * N_CLASSES + cl] + p1 * Wc[(ff + 1) * N_CLASSES + cl]
                     + p2 * Wc[(ff + 2) * N_CLASSES + cl] + p3 * Wc[(ff + 3) * N_CLASSES + cl];
            for (int st = 32; st > 0; st >>= 1) pr += __shfl_down(pr, st);
            if (tid == 0) logits[cl] = pr + bc[cl];
        }
        if (tid == 0) {
            float mx = logits[0];
            for (int cl = 1; cl < N_CLASSES; ++cl) mx = fmaxf(mx, logits[cl]);
            float sexp = 0.f;
            for (int cl = 0; cl < N_CLASSES; ++cl) sexp += expf(logits[cl] - mx);
            float lse = mx + logf(sexp);
            for (int cl = 0; cl < N_CLASSES; ++cl) {
                out[g * N_CLASSES + cl] = logits[cl];
                out[N_GRAPHS * N_CLASSES + g * N_CLASSES + cl] = logits[cl] - lse;
            }
        }
    }
}

// ---------------- launch ----------------
extern "C" void kernel_launch(void* const* d_in, const int* in_sizes, int n_in,
                              void* d_out, int out_size, void* d_ws, size_t ws_size,
                              hipStream_t stream) {
    const float* x    = (const float*)d_in[0];
    const int*   ei   = (const int*)d_in[1];
    const int*   src  = ei;
    const int*   dst  = ei + N_EDGES;
    const int*   batch= (const int*)d_in[2];
    const float* W1 = (const float*)d_in[3]; const float* b1 = (const float*)d_in[4];
    const float* W2 = (const float*)d_in[5]; const float* b2 = (const float*)d_in[6];
    const float* W3 = (const float*)d_in[7]; const float* b3 = (const float*)d_in[8];
    const float* Wc = (const float*)d_in[9]; const float* bc = (const float*)d_in[10];
    float* out = (float*)d_out;

    // allow 160 KB dynamic LDS for k_agg (idempotent, capture-safe)
    hipFuncSetAttribute(reinterpret_cast<const void*>(k_agg),
                        hipFuncAttributeMaxDynamicSharedMemorySize, NP8 + 16);

    char* ws = (char*)d_ws;
    size_t off = 0;
    auto alloc = [&](size_t bytes) -> char* {
        char* p = ws + off;
        off = (off + bytes + 255) & ~(size_t)255;
        return p;
    };
    int*    fill    = (int*)alloc(N_NODES * 4);      // zeroed by k_setup
    ushort* csr16   = (ushort*)alloc((size_t)N_NODES * SLOT * 2);  // 2.56 MB
    float*  dinv    = (float*)alloc(N_NODES * 4);
    int*    rlen4   = (int*)alloc(N_NODES * 4);
    ushort* Wt      = (ushort*)alloc((size_t)3 * 65536 * 2);
    ushort* xb      = (ushort*)alloc((size_t)N_NODES * DIM * 2);   // bf16 planes
    ushort* h1      = (ushort*)alloc((size_t)N_NODES * DIM * 2);   // bf16 planes
    unsigned char* h8 = (unsigned char*)alloc((size_t)N_NODES * DIM);  // fp8 planes

    k_setup<<<1101, 256, 0, stream>>>(x, xb, W1, W2, W3, Wt, fill);
    k_degfill<<<(N_EDGES + 255) / 256, 256, 0, stream>>>(src, dst, fill, csr16);
    k_dinv<<<(N_NODES + 255) / 256, 256, 0, stream>>>(fill, dinv, rlen4, csr16);

    const int agg_grid = N_CH * 8;         // 256 blocks, 1/CU, 160 KB LDS, 512 thr
    const int gemm_grid = N_NODES / 32;    // 625 blocks, 2 tiles each

    // conv1: h1 = relu(agg(xb @ W1) + b1)
    k_gemm<<<gemm_grid, 256, 0, stream>>>(xb, Wt, dinv, h8);
    k_agg<<<agg_grid, AGG_THR, NP8 + 16, stream>>>(h8, rlen4, csr16, dinv, b1, nullptr, h1, 0);
    // conv2: xb = relu(h1 + agg(h1 @ W2) + b2)
    k_gemm<<<gemm_grid, 256, 0, stream>>>(h1, Wt + 65536, dinv, h8);
    k_agg<<<agg_grid, AGG_THR, NP8 + 16, stream>>>(h8, rlen4, csr16, dinv, b2, h1, xb, 1);
    // conv3: h1 = agg(xb @ W3) + b3 (no relu), then pool
    k_gemm<<<gemm_grid, 256, 0, stream>>>(xb, Wt + 131072, dinv, h8);
    k_agg<<<agg_grid, AGG_THR, NP8 + 16, stream>>>(h8, rlen4, csr16, dinv, b3, nullptr, h1, 2);

    k_poolfinal<<<N_GRAPHS, 512, 0, stream>>>(h1, batch, Wc, bc, out);
}